// Round 10
// baseline (235.038 us; speedup 1.0000x reference)
//
#include <hip/hip_runtime.h>

constexpr int NB = 8, NA = 64, NT = 12, NH = 128, NTY = 8, NSC = 32, NAG = 16;

struct Params {
    const float *traj, *ntraj, *ty, *sd, *adata, *rel;
    const float *W_in, *b_in, *W_nt, *b_nt, *W_ag, *b_ag, *W_sc, *b_sc;
    const float *W_ein, *b_ein, *W_ety, *b_ety;
    const float *W_edge, *b_edge, *W_self, *b_self, *W_e2n, *b_e2n;
    const float *W_ih, *W_hh, *b_ih, *b_hh, *W_pred, *b_pred;
    float *h0, *h1, *c, *se0, *se1, *R0, *R1, *hsumA;
    float *Wty, *Wsc, *Wag, *Wcomb, *vbase, *vag, *vbe, *sesty, *Xs, *out;
};

// ---- Prelude: fold (blk 0-184) | r0+sesty+state-zero (blk 185-312, 4 rows/block) ----
// x layout for W_ih rows: [coord 0:128 | type 128:256 | node 256:384 | scene 384:512 | agent 512:640]
__global__ __launch_bounds__(512) void k_prelude(Params p) {
    const int blk = blockIdx.x, tid = threadIdx.x;
    if (blk < 185) {
        const int c = tid;
        __shared__ float lrow[NH];
        __shared__ float b1[NH], b2[NH], b3[NH], b4[NH];
        if (blk < 184) {
            const float* src; int ihoff, row; float* dst;
            if (blk < 8)       { row = blk;      src = p.W_nt  + row * NH; ihoff = 128; dst = p.Wty; }
            else if (blk < 40) { row = blk - 8;  src = p.W_sc  + row * NH; ihoff = 384; dst = p.Wsc; }
            else if (blk < 56) { row = blk - 40; src = p.W_ag  + row * NH; ihoff = 512; dst = p.Wag; }
            else               { row = blk - 56; src = p.W_e2n + row * NH; ihoff = 256; dst = p.Wcomb; }
            if (c < NH) lrow[c] = src[c];
            __syncthreads();
            float acc = 0.f;
            for (int k = 0; k < NH; ++k) acc += lrow[k] * p.W_ih[(ihoff + k) * 512 + c];
            dst[row * 512 + c] = acc;
        } else {
            if (c < NH) { b1[c] = p.b_nt[c]; b2[c] = p.b_sc[c]; b3[c] = p.b_ag[c]; b4[c] = p.b_e2n[c]; }
            __syncthreads();
            float vb = p.b_ih[c] + p.b_hh[c], va = 0.f, ve = 0.f;
            for (int k = 0; k < NH; ++k) {
                vb += b1[k] * p.W_ih[(128 + k) * 512 + c] + b2[k] * p.W_ih[(384 + k) * 512 + c];
                va += b3[k] * p.W_ih[(512 + k) * 512 + c];
                ve += b4[k] * p.W_ih[(256 + k) * 512 + c];
            }
            p.vbase[c] = vb; p.vag[c] = va; p.vbe[c] = ve;
        }
    } else {
        // R0 closed form + sesty + zero-init h0/c/se0 + zero hsumA, 4 rows/block.
        const int rel = blk - 185;
        const int r0g = rel * 4;
        const int b = r0g >> 6;
        const int q = tid >> 7, n = tid & 127;
        const int row = r0g + q, i = row & 63;
        __shared__ float lf[NA][6];
        __shared__ float lt[NA][NTY];
        __shared__ float sumf[6], sumt[NTY];
        if (tid < NA) {
            int j = tid, rj = b * NA + j;
            for (int k = 0; k < 3; ++k) {
                lf[j][k]     = p.ntraj[(rj * NT + 0) * 3 + k];
                lf[j][3 + k] = p.traj [(rj * NT + 0) * 3 + k];
            }
            for (int k = 0; k < NTY; ++k) lt[j][k] = p.ty[rj * NTY + k];
        }
        // zero-init carried state
        p.h0 [row * NH + n] = 0.f;
        p.c  [row * NH + n] = 0.f;
        p.se0[row * NH + n] = 0.f;
        if (rel < 26) p.hsumA[rel * 512 + tid] = 0.f;   // 26*512 = 13312 = 13 slots * 1024
        __syncthreads();
        if (tid < 6) {
            float s = 0.f; for (int j = 0; j < NA; ++j) s += lf[j][tid];
            sumf[tid] = s;
        } else if (tid < 6 + NTY) {
            int k = tid - 6; float s = 0.f;
            for (int j = 0; j < NA; ++j) s += lt[j][k];
            sumt[k] = s;
        }
        __syncthreads();
        float acc_i = p.b_ein[n] + p.b_ety[n];
        for (int k = 0; k < 6; ++k)   acc_i += lf[i][k] * p.W_ein[k * NH + n];
        for (int k = 0; k < NTY; ++k) acc_i += lt[i][k] * (p.W_ein[(12 + k) * NH + n] + p.W_ety[k * NH + n]);
        float acc_j = 0.f;
        for (int k = 0; k < 6; ++k)   acc_j += sumf[k] * p.W_ein[(6 + k) * NH + n];
        for (int k = 0; k < NTY; ++k) acc_j += sumt[k] * (p.W_ein[(20 + k) * NH + n] + p.W_ety[(NTY + k) * NH + n]);
        p.R0[row * NH + n] = 64.f * acc_i + acc_j;
        float sv = p.b_self[n];
        for (int k = 0; k < NTY; ++k) sv += lt[i][k] * p.W_self[(2 * NH + k) * NH + n];
        p.sesty[row * NH + n] = sv;
    }
}

// ---- X_static[(g,t), 512]; vbe folded in for t>0 ----
__global__ __launch_bounds__(512) void k_xstatic(Params p) {
    const int g = blockIdx.x, tid = threadIdx.x, b = g >> 6;
    __shared__ float coordL[NT][NH];
    __shared__ float sceneL[NT][NSC];
    __shared__ float agentL[NT][NAG];
    __shared__ float tyL[NTY];
    const float relv = p.rel[g];
    for (int idx = tid; idx < NT * NH; idx += 512) {
        int r = idx >> 7, k = idx & 127;
        float acc = p.b_in[k];
        const float* nt = p.ntraj + (g * NT + r) * 3;
        const float* tr = p.traj  + (g * NT + r) * 3;
        for (int j = 0; j < 3; ++j) acc += nt[j] * p.W_in[j * NH + k] + tr[j] * p.W_in[(3 + j) * NH + k];
        coordL[r][k] = fmaxf(acc, 0.f);
    }
    for (int i = tid; i < NT * NSC; i += 512) { int r = i >> 5, k = i & 31; sceneL[r][k] = p.sd[(b * NT + r) * NSC + k]; }
    for (int i = tid; i < NT * NAG; i += 512) { int r = i >> 4, k = i & 15; agentL[r][k] = p.adata[(g * NT + r) * NAG + k] * relv; }
    if (tid < NTY) tyL[tid] = p.ty[g * NTY + tid];
    __syncthreads();
    const int c = tid;
    float base = p.vbase[c] + relv * p.vag[c];
    for (int i = 0; i < NTY; ++i) base += tyL[i] * p.Wty[i * 512 + c];
    const float vbeL = p.vbe[c];
    float acc[NT];
#pragma unroll
    for (int r = 0; r < NT; ++r) acc[r] = base + (r > 0 ? vbeL : 0.f);
    for (int k = 0; k < NH; ++k) { float w = p.W_ih[k * 512 + c];
#pragma unroll
        for (int r = 0; r < NT; ++r) acc[r] += coordL[r][k] * w; }
    for (int k = 0; k < NSC; ++k) { float w = p.Wsc[k * 512 + c];
#pragma unroll
        for (int r = 0; r < NT; ++r) acc[r] += sceneL[r][k] * w; }
    for (int k = 0; k < NAG; ++k) { float w = p.Wag[k * 512 + c];
#pragma unroll
        for (int r = 0; r < NT; ++r) acc[r] += agentL[r][k] * w; }
#pragma unroll
    for (int r = 0; r < NT; ++r) p.Xs[((size_t)(g * NT + r)) * 512 + c] = acc[r];
}

// ---- One recurrence step: block = (row-quad, unit-half); 256 blocks x 1024 threads ----
// Gates computed only for this block's 256 gate cols (units ch*64..+63).
// hsum via atomics into hsumA[t+1]; out[t-1] computed from hprev (deferred).
// t == NT: tail launch, emits out[NT-1] only.
__global__ __launch_bounds__(1024) void k_step(Params p, int t) {
    const int tid = threadIdx.x;
    const int rq = blockIdx.x >> 1, ch = blockIdx.x & 1;
    const int r0 = rq * 4;
    const int b = r0 >> 6;
    const int n = tid & 127;
    const float* __restrict__ hcur = (t & 1) ? p.h1 : p.h0;
    float* hnxt = (t & 1) ? p.h0 : p.h1;
    const float* __restrict__ Rcur = (t & 1) ? p.R1 : p.R0;
    float* Rnxt = (t & 1) ? p.R0 : p.R1;
    const float* __restrict__ secur = (t & 1) ? p.se1 : p.se0;
    float* senxt = (t & 1) ? p.se0 : p.se1;

    __shared__ float lh[4][NH], lR[4][NH], lse[4][NH];
    __shared__ float hsumL[NH];
    __shared__ float psA[16][NH];            // stage A partials [path*4+row]
    __shared__ float ps2[8][NH];             // shw2 partials
    __shared__ float psO[2][4][NH];          // out-proj partials
    __shared__ float lagg[4][NH];
    __shared__ float lgp[2][4][256];         // gate partials [khalf][row][cc]

    // ---- Tail: out[NT-1] from hcur ----
    if (t == NT) {
        if (ch == 1) return;
        if (tid < 512) lh[tid >> 7][tid & 127] = hcur[(r0 + (tid >> 7)) * NH + (tid & 127)];
        __syncthreads();
        {
            const int kh = tid >> 9, row = (tid >> 7) & 3;
            float s = 0.f;
            const float* wp = p.W_pred + n;
#pragma unroll 8
            for (int k = 64 * kh; k < 64 * kh + 64; ++k) s += lh[row][k] * wp[k * NH];
            psO[kh][row][n] = s;
        }
        __syncthreads();
        if (tid < 512) {
            const int row = tid >> 7, k = tid & 127;
            float v = psO[0][row][k] + psO[1][row][k] + p.b_pred[k];
            p.out[((size_t)(r0 + row) * NT + (NT - 1)) * NH + k] = fmaxf(v, 0.f);
        }
        return;
    }

    // Phase 0: own-row state loads (full width) + hsum vector load.
    if (tid < 512) {
        const int rr = tid >> 7, k = tid & 127;
        lh [rr][k] = hcur [(r0 + rr) * NH + k];
        lR [rr][k] = Rcur [(r0 + rr) * NH + k];
        lse[rr][k] = secur[(r0 + rr) * NH + k];
    } else if ((tid >> 7) == 4) {
        hsumL[tid & 127] = p.hsumA[(size_t)t * (NB * NH) + b * NH + (tid & 127)];
    }
    __syncthreads();                          // B1

    // Phase 1: stage A partials + shw2 partials + (ch0,t>0) out-proj partials.
    {
        const int path = tid >> 8, rp = (tid >> 7) & 1;
        const float* wb; const float* d0; const float* d1;
        if (path == 0)      { wb = p.W_edge + n;               d0 = lh[2 * rp];  d1 = lh[2 * rp + 1];  }
        else if (path == 1) { wb = p.W_edge + 2 * NH * NH + n; d0 = lR[2 * rp];  d1 = lR[2 * rp + 1];  }
        else if (path == 2) { wb = p.W_self + n;               d0 = lh[2 * rp];  d1 = lh[2 * rp + 1];  }
        else                { wb = p.W_self + NH * NH + n;     d0 = lse[2 * rp]; d1 = lse[2 * rp + 1]; }
        float a0 = 0.f, a1 = 0.f;
#pragma unroll 8
        for (int k = 0; k < NH; ++k) {
            float w = wb[k * NH];
            a0 += d0[k] * w; a1 += d1[k] * w;
        }
        psA[path * 4 + 2 * rp + 0][n] = a0;
        psA[path * 4 + 2 * rp + 1][n] = a1;
    }
    {
        const int ks = tid >> 7;              // 0..7
        float s = 0.f;
        const float* w2 = p.W_edge + NH * NH + n;
#pragma unroll
        for (int k = 16 * ks; k < 16 * ks + 16; ++k) s += hsumL[k] * w2[k * NH];
        ps2[ks][n] = s;
    }
    if (ch == 0 && t > 0) {
        const int kh = tid >> 9, row = (tid >> 7) & 3;
        float s = 0.f;
        const float* wp = p.W_pred + n;
#pragma unroll 8
        for (int k = 64 * kh; k < 64 * kh + 64; ++k) s += lh[row][k] * wp[k * NH];
        psO[kh][row][n] = s;
    }
    __syncthreads();                          // B2

    // Phase 2: combine A (R_new/se_new/agg, full width) + out[t-1] write.
    if (tid < 512) {
        const int rr = tid >> 7, k = tid & 127;
        float shw2v = ps2[0][k] + ps2[1][k] + ps2[2][k] + ps2[3][k]
                    + ps2[4][k] + ps2[5][k] + ps2[6][k] + ps2[7][k];
        float a1v = psA[0 + rr][k];
        float a3v = psA[4 + rr][k];
        float aSv = psA[8 + rr][k] + psA[12 + rr][k];
        float Rn = 64.f * a1v + shw2v + a3v + 64.f * p.b_edge[k];
        float Sn = aSv + p.sesty[(r0 + rr) * NH + k];
        if (ch == 0) {
            Rnxt [(r0 + rr) * NH + k] = Rn;
            senxt[(r0 + rr) * NH + k] = Sn;
        }
        lagg[rr][k] = Rn + Sn;
    } else if (ch == 0 && t > 0) {
        const int rc = tid - 512, row = rc >> 7, k = rc & 127;
        float v = psO[0][row][k] + psO[1][row][k] + p.b_pred[k];
        p.out[((size_t)(r0 + row) * NT + (t - 1)) * NH + k] = fmaxf(v, 0.f);
    }
    __syncthreads();                          // B3

    // Phase 3: gates for this block's 256 cols; 2 K-halves; 2 rows/thread.
    {
        const int cc = tid & 255;             // qq*64 + u
        const int kh = (tid >> 8) & 1;
        const int rp = tid >> 9;
        const int col = ((cc >> 6) << 7) + (ch << 6) + (cc & 63);
        float a0 = 0.f, a1 = 0.f;
        if (kh == 0) {
            a0 = p.Xs[((size_t)(r0 + 2 * rp) * NT + t) * 512 + col];
            a1 = p.Xs[((size_t)(r0 + 2 * rp + 1) * NT + t) * 512 + col];
        }
        if (t > 0) {
            const float* wc = p.Wcomb + col;
            const float* wh = p.W_hh + col;
#pragma unroll 8
            for (int k = 64 * kh; k < 64 * kh + 64; ++k) {
                float w = wc[k * 512];
                a0 += lagg[2 * rp][k] * w; a1 += lagg[2 * rp + 1][k] * w;
            }
#pragma unroll 8
            for (int k = 64 * kh; k < 64 * kh + 64; ++k) {
                float w = wh[k * 512];
                a0 += lh[2 * rp][k] * w; a1 += lh[2 * rp + 1][k] * w;
            }
        }
        lgp[kh][2 * rp][cc] = a0;
        lgp[kh][2 * rp + 1][cc] = a1;
    }
    __syncthreads();                          // B4

    // Phase 4: LSTM for this block's 64 units x 4 rows; publish h + hsum atomics.
    if (tid < 256) {
        const int row = tid >> 6, u = tid & 63;
        const int unit = (ch << 6) | u;
        const int g = r0 + row;
        const int idx = g * NH + unit;
        float gi = lgp[0][row][u]        + lgp[1][row][u];
        float gf = lgp[0][row][64 + u]   + lgp[1][row][64 + u];
        float gg = lgp[0][row][128 + u]  + lgp[1][row][128 + u];
        float go = lgp[0][row][192 + u]  + lgp[1][row][192 + u];
        float si = 1.f / (1.f + expf(-gi));
        float sf = 1.f / (1.f + expf(-gf));
        float so = 1.f / (1.f + expf(-go));
        float cn = sf * p.c[idx] + si * tanhf(gg);
        float hn = so * tanhf(cn);
        p.c[idx] = cn;
        hnxt[idx] = hn;
        if (t + 1 < NT) atomicAdd(&p.hsumA[(size_t)(t + 1) * (NB * NH) + b * NH + unit], hn);
    }
}

extern "C" void kernel_launch(void* const* d_in, const int* in_sizes, int n_in,
                              void* d_out, int out_size, void* d_ws, size_t ws_size,
                              hipStream_t stream) {
    const float* const* in = (const float* const*)d_in;
    Params p;
    p.traj = in[0]; p.ntraj = in[1]; p.ty = in[2]; p.sd = in[3]; p.adata = in[4]; p.rel = in[5];
    p.W_in = in[6]; p.b_in = in[7]; p.W_nt = in[8]; p.b_nt = in[9];
    p.W_ag = in[10]; p.b_ag = in[11]; p.W_sc = in[12]; p.b_sc = in[13];
    p.W_ein = in[14]; p.b_ein = in[15]; p.W_ety = in[16]; p.b_ety = in[17];
    p.W_edge = in[18]; p.b_edge = in[19]; p.W_self = in[20]; p.b_self = in[21];
    p.W_e2n = in[22]; p.b_e2n = in[23];
    p.W_ih = in[24]; p.W_hh = in[25]; p.b_ih = in[26]; p.b_hh = in[27];
    p.W_pred = in[28]; p.b_pred = in[29];

    float* ws = (float*)d_ws;
    const size_t S = (size_t)NB * NA * NH;   // 65536
    p.h0  = ws;               // zeroed by k_prelude
    p.h1  = ws + S;           // written at t=0 before read
    p.c   = ws + 2 * S;       // zeroed by k_prelude
    p.se0 = ws + 3 * S;       // zeroed by k_prelude
    p.se1 = ws + 4 * S;       // written t=0 before read
    p.R0  = ws + 5 * S;       // k_prelude
    p.R1  = ws + 6 * S;       // written t=0 before read
    p.sesty = ws + 7 * S;
    p.hsumA = ws + 8 * S;     // 13 slots * 1024, zeroed by k_prelude
    float* w = ws + 8 * S + 13 * (NB * NH);
    p.Wty   = w;              w += 8 * 512;
    p.Wsc   = w;              w += 32 * 512;
    p.Wag   = w;              w += 16 * 512;
    p.Wcomb = w;              w += 128 * 512;
    p.vbase = w;              w += 512;
    p.vag   = w;              w += 512;
    p.vbe   = w;              w += 512;
    p.Xs    = w;              w += (size_t)NB * NA * NT * 512;
    p.out = (float*)d_out;

    k_prelude<<<313, 512, 0, stream>>>(p);                     // fold | r0 | zeros
    k_xstatic<<<NB * NA, 512, 0, stream>>>(p);
    for (int t = 0; t < NT; ++t)
        k_step<<<256, 1024, 0, stream>>>(p, t);
    k_step<<<256, 1024, 0, stream>>>(p, NT);                   // tail: out[11]
}

// Round 11
// 226.862 us; speedup vs baseline: 1.0360x; 1.0360x over previous
//
#include <hip/hip_runtime.h>

constexpr int NB = 8, NA = 64, NT = 12, NH = 128, NTY = 8, NSC = 32, NAG = 16;

struct Params {
    const float *traj, *ntraj, *ty, *sd, *adata, *rel;
    const float *W_in, *b_in, *W_nt, *b_nt, *W_ag, *b_ag, *W_sc, *b_sc;
    const float *W_ein, *b_ein, *W_ety, *b_ety;
    const float *W_edge, *b_edge, *W_self, *b_self, *W_e2n, *b_e2n;
    const float *W_ih, *W_hh, *b_ih, *b_hh, *W_pred, *b_pred;
    float *h0, *h1, *c, *se0, *se1, *R0, *R1;
    float *Wty, *Wsc, *Wag, *Wcomb, *vbase, *vag, *vbe, *sesty, *Xs, *out;
};

// ---- Prelude: fold (blk 0-184) | r0+sesty+state-zero (blk 185-312, 4 rows/block) ----
// x layout for W_ih rows: [coord 0:128 | type 128:256 | node 256:384 | scene 384:512 | agent 512:640]
__global__ __launch_bounds__(512) void k_prelude(Params p) {
    const int blk = blockIdx.x, tid = threadIdx.x;
    if (blk < 185) {
        const int c = tid;
        __shared__ float lrow[NH];
        __shared__ float b1[NH], b2[NH], b3[NH], b4[NH];
        if (blk < 184) {
            const float* src; int ihoff, row; float* dst;
            if (blk < 8)       { row = blk;      src = p.W_nt  + row * NH; ihoff = 128; dst = p.Wty; }
            else if (blk < 40) { row = blk - 8;  src = p.W_sc  + row * NH; ihoff = 384; dst = p.Wsc; }
            else if (blk < 56) { row = blk - 40; src = p.W_ag  + row * NH; ihoff = 512; dst = p.Wag; }
            else               { row = blk - 56; src = p.W_e2n + row * NH; ihoff = 256; dst = p.Wcomb; }
            if (c < NH) lrow[c] = src[c];
            __syncthreads();
            float acc = 0.f;
            for (int k = 0; k < NH; ++k) acc += lrow[k] * p.W_ih[(ihoff + k) * 512 + c];
            dst[row * 512 + c] = acc;
        } else {
            if (c < NH) { b1[c] = p.b_nt[c]; b2[c] = p.b_sc[c]; b3[c] = p.b_ag[c]; b4[c] = p.b_e2n[c]; }
            __syncthreads();
            float vb = p.b_ih[c] + p.b_hh[c], va = 0.f, ve = 0.f;
            for (int k = 0; k < NH; ++k) {
                vb += b1[k] * p.W_ih[(128 + k) * 512 + c] + b2[k] * p.W_ih[(384 + k) * 512 + c];
                va += b3[k] * p.W_ih[(512 + k) * 512 + c];
                ve += b4[k] * p.W_ih[(256 + k) * 512 + c];
            }
            p.vbase[c] = vb; p.vag[c] = va; p.vbe[c] = ve;
        }
    } else {
        // R0 closed form + sesty + zero-init h0/c/se0, 4 rows/block.
        const int rel = blk - 185;
        const int r0g = rel * 4;
        const int b = r0g >> 6;
        const int q = tid >> 7, n = tid & 127;
        const int row = r0g + q, i = row & 63;
        __shared__ float lf[NA][6];
        __shared__ float lt[NA][NTY];
        __shared__ float sumf[6], sumt[NTY];
        if (tid < NA) {
            int j = tid, rj = b * NA + j;
            for (int k = 0; k < 3; ++k) {
                lf[j][k]     = p.ntraj[(rj * NT + 0) * 3 + k];
                lf[j][3 + k] = p.traj [(rj * NT + 0) * 3 + k];
            }
            for (int k = 0; k < NTY; ++k) lt[j][k] = p.ty[rj * NTY + k];
        }
        // zero-init carried state
        p.h0 [row * NH + n] = 0.f;
        p.c  [row * NH + n] = 0.f;
        p.se0[row * NH + n] = 0.f;
        __syncthreads();
        if (tid < 6) {
            float s = 0.f; for (int j = 0; j < NA; ++j) s += lf[j][tid];
            sumf[tid] = s;
        } else if (tid < 6 + NTY) {
            int k = tid - 6; float s = 0.f;
            for (int j = 0; j < NA; ++j) s += lt[j][k];
            sumt[k] = s;
        }
        __syncthreads();
        float acc_i = p.b_ein[n] + p.b_ety[n];
        for (int k = 0; k < 6; ++k)   acc_i += lf[i][k] * p.W_ein[k * NH + n];
        for (int k = 0; k < NTY; ++k) acc_i += lt[i][k] * (p.W_ein[(12 + k) * NH + n] + p.W_ety[k * NH + n]);
        float acc_j = 0.f;
        for (int k = 0; k < 6; ++k)   acc_j += sumf[k] * p.W_ein[(6 + k) * NH + n];
        for (int k = 0; k < NTY; ++k) acc_j += sumt[k] * (p.W_ein[(20 + k) * NH + n] + p.W_ety[(NTY + k) * NH + n]);
        p.R0[row * NH + n] = 64.f * acc_i + acc_j;
        float sv = p.b_self[n];
        for (int k = 0; k < NTY; ++k) sv += lt[i][k] * p.W_self[(2 * NH + k) * NH + n];
        p.sesty[row * NH + n] = sv;
    }
}

// ---- X_static[(g,t), 512]; vbe folded in for t>0 ----
__global__ __launch_bounds__(512) void k_xstatic(Params p) {
    const int g = blockIdx.x, tid = threadIdx.x, b = g >> 6;
    __shared__ float coordL[NT][NH];
    __shared__ float sceneL[NT][NSC];
    __shared__ float agentL[NT][NAG];
    __shared__ float tyL[NTY];
    const float relv = p.rel[g];
    for (int idx = tid; idx < NT * NH; idx += 512) {
        int r = idx >> 7, k = idx & 127;
        float acc = p.b_in[k];
        const float* nt = p.ntraj + (g * NT + r) * 3;
        const float* tr = p.traj  + (g * NT + r) * 3;
        for (int j = 0; j < 3; ++j) acc += nt[j] * p.W_in[j * NH + k] + tr[j] * p.W_in[(3 + j) * NH + k];
        coordL[r][k] = fmaxf(acc, 0.f);
    }
    for (int i = tid; i < NT * NSC; i += 512) { int r = i >> 5, k = i & 31; sceneL[r][k] = p.sd[(b * NT + r) * NSC + k]; }
    for (int i = tid; i < NT * NAG; i += 512) { int r = i >> 4, k = i & 15; agentL[r][k] = p.adata[(g * NT + r) * NAG + k] * relv; }
    if (tid < NTY) tyL[tid] = p.ty[g * NTY + tid];
    __syncthreads();
    const int c = tid;
    float base = p.vbase[c] + relv * p.vag[c];
    for (int i = 0; i < NTY; ++i) base += tyL[i] * p.Wty[i * 512 + c];
    const float vbeL = p.vbe[c];
    float acc[NT];
#pragma unroll
    for (int r = 0; r < NT; ++r) acc[r] = base + (r > 0 ? vbeL : 0.f);
    for (int k = 0; k < NH; ++k) { float w = p.W_ih[k * 512 + c];
#pragma unroll
        for (int r = 0; r < NT; ++r) acc[r] += coordL[r][k] * w; }
    for (int k = 0; k < NSC; ++k) { float w = p.Wsc[k * 512 + c];
#pragma unroll
        for (int r = 0; r < NT; ++r) acc[r] += sceneL[r][k] * w; }
    for (int k = 0; k < NAG; ++k) { float w = p.Wag[k * 512 + c];
#pragma unroll
        for (int r = 0; r < NT; ++r) acc[r] += agentL[r][k] * w; }
#pragma unroll
    for (int r = 0; r < NT; ++r) p.Xs[((size_t)(g * NT + r)) * 512 + c] = acc[r];
}

// ---- One recurrence step: block = (row-quad, unit-half); 256 blocks x 1024 threads ----
// Gates computed only for this block's 256 gate cols (units ch*64..+63).
// hsum from direct hcur reads (NO atomics); out[t-1] from hcur (deferred).
// t == NT: tail launch, emits out[NT-1] only.
__global__ __launch_bounds__(1024) void k_step(Params p, int t) {
    const int tid = threadIdx.x;
    const int rq = blockIdx.x >> 1, ch = blockIdx.x & 1;
    const int r0 = rq * 4;
    const int b = r0 >> 6;
    const int n = tid & 127;
    const int g8 = tid >> 7;                 // 0..7
    const float* __restrict__ hcur = (t & 1) ? p.h1 : p.h0;
    float* hnxt = (t & 1) ? p.h0 : p.h1;
    const float* __restrict__ Rcur = (t & 1) ? p.R1 : p.R0;
    float* Rnxt = (t & 1) ? p.R0 : p.R1;
    const float* __restrict__ secur = (t & 1) ? p.se1 : p.se0;
    float* senxt = (t & 1) ? p.se0 : p.se1;

    __shared__ float lh[4][NH], lR[4][NH], lse[4][NH];
    __shared__ float psum[8][NH];            // batch h-sum partials
    __shared__ float psA[16][NH];            // stage A partials [path*4+row]
    __shared__ float ps2[8][NH];             // shw2 partials
    __shared__ float psO[2][4][NH];          // out-proj partials
    __shared__ float lagg[4][NH];
    __shared__ float lgp[2][4][256];         // gate partials [khalf][row][cc]

    // ---- Tail: out[NT-1] from hcur ----
    if (t == NT) {
        if (ch == 1) return;
        if (tid < 512) lh[tid >> 7][tid & 127] = hcur[(r0 + (tid >> 7)) * NH + (tid & 127)];
        __syncthreads();
        {
            const int kh = tid >> 9, row = (tid >> 7) & 3;
            float s = 0.f;
            const float* wp = p.W_pred + n;
#pragma unroll 8
            for (int k = 64 * kh; k < 64 * kh + 64; ++k) s += lh[row][k] * wp[k * NH];
            psO[kh][row][n] = s;
        }
        __syncthreads();
        if (tid < 512) {
            const int row = tid >> 7, k = tid & 127;
            float v = psO[0][row][k] + psO[1][row][k] + p.b_pred[k];
            p.out[((size_t)(r0 + row) * NT + (NT - 1)) * NH + k] = fmaxf(v, 0.f);
        }
        return;
    }

    // Phase 0: batch h-sum partials (all threads) + own-row state loads.
    if (t > 0) {
        float s = 0.f;
        const float* hb = hcur + (b * NA + g8 * 8) * NH + n;
#pragma unroll
        for (int j = 0; j < 8; ++j) s += hb[j * NH];
        psum[g8][n] = s;
    }
    if (tid < 512) {
        const int rr = tid >> 7, k = tid & 127;
        lh [rr][k] = hcur [(r0 + rr) * NH + k];
        lR [rr][k] = Rcur [(r0 + rr) * NH + k];
        lse[rr][k] = secur[(r0 + rr) * NH + k];
    }
    __syncthreads();                          // B1

    // Phase 1: stage A partials + shw2 partials + (ch0,t>0) out-proj partials.
    {
        const int path = tid >> 8, rp = (tid >> 7) & 1;
        const float* wb; const float* d0; const float* d1;
        if (path == 0)      { wb = p.W_edge + n;               d0 = lh[2 * rp];  d1 = lh[2 * rp + 1];  }
        else if (path == 1) { wb = p.W_edge + 2 * NH * NH + n; d0 = lR[2 * rp];  d1 = lR[2 * rp + 1];  }
        else if (path == 2) { wb = p.W_self + n;               d0 = lh[2 * rp];  d1 = lh[2 * rp + 1];  }
        else                { wb = p.W_self + NH * NH + n;     d0 = lse[2 * rp]; d1 = lse[2 * rp + 1]; }
        float a0 = 0.f, a1 = 0.f;
#pragma unroll 8
        for (int k = 0; k < NH; ++k) {
            float w = wb[k * NH];
            a0 += d0[k] * w; a1 += d1[k] * w;
        }
        psA[path * 4 + 2 * rp + 0][n] = a0;
        psA[path * 4 + 2 * rp + 1][n] = a1;
    }
    if (t > 0) {
        const int ks = g8;                    // 0..7
        float s = 0.f;
        const float* w2 = p.W_edge + NH * NH + n;
#pragma unroll
        for (int k = 16 * ks; k < 16 * ks + 16; ++k) {
            float hv = psum[0][k] + psum[1][k] + psum[2][k] + psum[3][k]
                     + psum[4][k] + psum[5][k] + psum[6][k] + psum[7][k];
            s += hv * w2[k * NH];
        }
        ps2[ks][n] = s;
    }
    if (ch == 0 && t > 0) {
        const int kh = tid >> 9, row = (tid >> 7) & 3;
        float s = 0.f;
        const float* wp = p.W_pred + n;
#pragma unroll 8
        for (int k = 64 * kh; k < 64 * kh + 64; ++k) s += lh[row][k] * wp[k * NH];
        psO[kh][row][n] = s;
    }
    __syncthreads();                          // B2

    // Phase 2: combine A (R_new/se_new/agg, full width) + out[t-1] write.
    if (tid < 512) {
        const int rr = tid >> 7, k = tid & 127;
        float shw2v = 0.f;
        if (t > 0)
            shw2v = ps2[0][k] + ps2[1][k] + ps2[2][k] + ps2[3][k]
                  + ps2[4][k] + ps2[5][k] + ps2[6][k] + ps2[7][k];
        float a1v = psA[0 + rr][k];
        float a3v = psA[4 + rr][k];
        float aSv = psA[8 + rr][k] + psA[12 + rr][k];
        float Rn = 64.f * a1v + shw2v + a3v + 64.f * p.b_edge[k];
        float Sn = aSv + p.sesty[(r0 + rr) * NH + k];
        if (ch == 0) {
            Rnxt [(r0 + rr) * NH + k] = Rn;
            senxt[(r0 + rr) * NH + k] = Sn;
        }
        lagg[rr][k] = Rn + Sn;
    } else if (ch == 0 && t > 0) {
        const int rc = tid - 512, row = rc >> 7, k = rc & 127;
        float v = psO[0][row][k] + psO[1][row][k] + p.b_pred[k];
        p.out[((size_t)(r0 + row) * NT + (t - 1)) * NH + k] = fmaxf(v, 0.f);
    }
    __syncthreads();                          // B3

    // Phase 3: gates for this block's 256 cols; 2 K-halves; 2 rows/thread.
    {
        const int cc = tid & 255;             // qq*64 + u
        const int kh = (tid >> 8) & 1;
        const int rp = tid >> 9;
        const int col = ((cc >> 6) << 7) + (ch << 6) + (cc & 63);
        float a0 = 0.f, a1 = 0.f;
        if (kh == 0) {
            a0 = p.Xs[((size_t)(r0 + 2 * rp) * NT + t) * 512 + col];
            a1 = p.Xs[((size_t)(r0 + 2 * rp + 1) * NT + t) * 512 + col];
        }
        if (t > 0) {
            const float* wc = p.Wcomb + col;
            const float* wh = p.W_hh + col;
#pragma unroll 8
            for (int k = 64 * kh; k < 64 * kh + 64; ++k) {
                float w = wc[k * 512];
                a0 += lagg[2 * rp][k] * w; a1 += lagg[2 * rp + 1][k] * w;
            }
#pragma unroll 8
            for (int k = 64 * kh; k < 64 * kh + 64; ++k) {
                float w = wh[k * 512];
                a0 += lh[2 * rp][k] * w; a1 += lh[2 * rp + 1][k] * w;
            }
        }
        lgp[kh][2 * rp][cc] = a0;
        lgp[kh][2 * rp + 1][cc] = a1;
    }
    __syncthreads();                          // B4

    // Phase 4: LSTM for this block's 64 units x 4 rows; publish h.
    if (tid < 256) {
        const int row = tid >> 6, u = tid & 63;
        const int unit = (ch << 6) | u;
        const int g = r0 + row;
        const int idx = g * NH + unit;
        float gi = lgp[0][row][u]        + lgp[1][row][u];
        float gf = lgp[0][row][64 + u]   + lgp[1][row][64 + u];
        float gg = lgp[0][row][128 + u]  + lgp[1][row][128 + u];
        float go = lgp[0][row][192 + u]  + lgp[1][row][192 + u];
        float si = 1.f / (1.f + expf(-gi));
        float sf = 1.f / (1.f + expf(-gf));
        float so = 1.f / (1.f + expf(-go));
        float cn = sf * p.c[idx] + si * tanhf(gg);
        float hn = so * tanhf(cn);
        p.c[idx] = cn;
        hnxt[idx] = hn;
    }
}

extern "C" void kernel_launch(void* const* d_in, const int* in_sizes, int n_in,
                              void* d_out, int out_size, void* d_ws, size_t ws_size,
                              hipStream_t stream) {
    const float* const* in = (const float* const*)d_in;
    Params p;
    p.traj = in[0]; p.ntraj = in[1]; p.ty = in[2]; p.sd = in[3]; p.adata = in[4]; p.rel = in[5];
    p.W_in = in[6]; p.b_in = in[7]; p.W_nt = in[8]; p.b_nt = in[9];
    p.W_ag = in[10]; p.b_ag = in[11]; p.W_sc = in[12]; p.b_sc = in[13];
    p.W_ein = in[14]; p.b_ein = in[15]; p.W_ety = in[16]; p.b_ety = in[17];
    p.W_edge = in[18]; p.b_edge = in[19]; p.W_self = in[20]; p.b_self = in[21];
    p.W_e2n = in[22]; p.b_e2n = in[23];
    p.W_ih = in[24]; p.W_hh = in[25]; p.b_ih = in[26]; p.b_hh = in[27];
    p.W_pred = in[28]; p.b_pred = in[29];

    float* ws = (float*)d_ws;
    const size_t S = (size_t)NB * NA * NH;   // 65536
    p.h0  = ws;               // zeroed by k_prelude
    p.h1  = ws + S;           // written at t=0 before read
    p.c   = ws + 2 * S;       // zeroed by k_prelude
    p.se0 = ws + 3 * S;       // zeroed by k_prelude
    p.se1 = ws + 4 * S;       // written t=0 before read
    p.R0  = ws + 5 * S;       // k_prelude
    p.R1  = ws + 6 * S;       // written t=0 before read
    p.sesty = ws + 7 * S;
    float* w = ws + 8 * S;
    p.Wty   = w;              w += 8 * 512;
    p.Wsc   = w;              w += 32 * 512;
    p.Wag   = w;              w += 16 * 512;
    p.Wcomb = w;              w += 128 * 512;
    p.vbase = w;              w += 512;
    p.vag   = w;              w += 512;
    p.vbe   = w;              w += 512;
    p.Xs    = w;              w += (size_t)NB * NA * NT * 512;
    p.out = (float*)d_out;

    k_prelude<<<313, 512, 0, stream>>>(p);                     // fold | r0 | zeros
    k_xstatic<<<NB * NA, 512, 0, stream>>>(p);
    for (int t = 0; t < NT; ++t)
        k_step<<<256, 1024, 0, stream>>>(p, t);
    k_step<<<256, 1024, 0, stream>>>(p, NT);                   // tail: out[11]
}

// Round 12
// 192.238 us; speedup vs baseline: 1.2226x; 1.1801x over previous
//
#include <hip/hip_runtime.h>

constexpr int NB = 8, NA = 64, NT = 12, NH = 128, NTY = 8, NSC = 32, NAG = 16;

struct Params {
    const float *traj, *ntraj, *ty, *sd, *adata, *rel;
    const float *W_in, *b_in, *W_nt, *b_nt, *W_ag, *b_ag, *W_sc, *b_sc;
    const float *W_ein, *b_ein, *W_ety, *b_ety;
    const float *W_edge, *b_edge, *W_self, *b_self, *W_e2n, *b_e2n;
    const float *W_ih, *W_hh, *b_ih, *b_hh, *W_pred, *b_pred;
    float *h0, *h1, *c, *se, *R;
    float *Wty, *Wsc, *Wag, *Wcomb, *vbase, *vag, *vbe, *sesty, *Xs, *out;
};

// ---- Prelude: fold (blk 0-184) | r0+sesty+state-zero (blk 185-312, 4 rows/block) ----
// x layout for W_ih rows: [coord 0:128 | type 128:256 | node 256:384 | scene 384:512 | agent 512:640]
__global__ __launch_bounds__(512) void k_prelude(Params p) {
    const int blk = blockIdx.x, tid = threadIdx.x;
    if (blk < 185) {
        const int c = tid;
        __shared__ float lrow[NH];
        __shared__ float b1[NH], b2[NH], b3[NH], b4[NH];
        if (blk < 184) {
            const float* src; int ihoff, row; float* dst;
            if (blk < 8)       { row = blk;      src = p.W_nt  + row * NH; ihoff = 128; dst = p.Wty; }
            else if (blk < 40) { row = blk - 8;  src = p.W_sc  + row * NH; ihoff = 384; dst = p.Wsc; }
            else if (blk < 56) { row = blk - 40; src = p.W_ag  + row * NH; ihoff = 512; dst = p.Wag; }
            else               { row = blk - 56; src = p.W_e2n + row * NH; ihoff = 256; dst = p.Wcomb; }
            if (c < NH) lrow[c] = src[c];
            __syncthreads();
            float acc = 0.f;
            for (int k = 0; k < NH; ++k) acc += lrow[k] * p.W_ih[(ihoff + k) * 512 + c];
            dst[row * 512 + c] = acc;
        } else {
            if (c < NH) { b1[c] = p.b_nt[c]; b2[c] = p.b_sc[c]; b3[c] = p.b_ag[c]; b4[c] = p.b_e2n[c]; }
            __syncthreads();
            float vb = p.b_ih[c] + p.b_hh[c], va = 0.f, ve = 0.f;
            for (int k = 0; k < NH; ++k) {
                vb += b1[k] * p.W_ih[(128 + k) * 512 + c] + b2[k] * p.W_ih[(384 + k) * 512 + c];
                va += b3[k] * p.W_ih[(512 + k) * 512 + c];
                ve += b4[k] * p.W_ih[(256 + k) * 512 + c];
            }
            p.vbase[c] = vb; p.vag[c] = va; p.vbe[c] = ve;
        }
    } else {
        // R0 closed form + sesty + zero-init h0/c/se, 4 rows/block.
        const int r0g = (blk - 185) * 4;
        const int b = r0g >> 6;
        const int q = tid >> 7, n = tid & 127;
        const int row = r0g + q, i = row & 63;
        __shared__ float lf[NA][6];
        __shared__ float lt[NA][NTY];
        __shared__ float sumf[6], sumt[NTY];
        if (tid < NA) {
            int j = tid, rj = b * NA + j;
            for (int k = 0; k < 3; ++k) {
                lf[j][k]     = p.ntraj[(rj * NT + 0) * 3 + k];
                lf[j][3 + k] = p.traj [(rj * NT + 0) * 3 + k];
            }
            for (int k = 0; k < NTY; ++k) lt[j][k] = p.ty[rj * NTY + k];
        }
        // zero-init carried state (replaces hipMemsetAsync)
        p.h0[row * NH + n] = 0.f;
        p.c [row * NH + n] = 0.f;
        p.se[row * NH + n] = 0.f;
        __syncthreads();
        if (tid < 6) {
            float s = 0.f; for (int j = 0; j < NA; ++j) s += lf[j][tid];
            sumf[tid] = s;
        } else if (tid < 6 + NTY) {
            int k = tid - 6; float s = 0.f;
            for (int j = 0; j < NA; ++j) s += lt[j][k];
            sumt[k] = s;
        }
        __syncthreads();
        float acc_i = p.b_ein[n] + p.b_ety[n];
        for (int k = 0; k < 6; ++k)   acc_i += lf[i][k] * p.W_ein[k * NH + n];
        for (int k = 0; k < NTY; ++k) acc_i += lt[i][k] * (p.W_ein[(12 + k) * NH + n] + p.W_ety[k * NH + n]);
        float acc_j = 0.f;
        for (int k = 0; k < 6; ++k)   acc_j += sumf[k] * p.W_ein[(6 + k) * NH + n];
        for (int k = 0; k < NTY; ++k) acc_j += sumt[k] * (p.W_ein[(20 + k) * NH + n] + p.W_ety[(NTY + k) * NH + n]);
        p.R[row * NH + n] = 64.f * acc_i + acc_j;
        float sv = p.b_self[n];
        for (int k = 0; k < NTY; ++k) sv += lt[i][k] * p.W_self[(2 * NH + k) * NH + n];
        p.sesty[row * NH + n] = sv;
    }
}

// ---- X_static[(g,t), 512]; vbe folded in for t>0 ----
__global__ __launch_bounds__(512) void k_xstatic(Params p) {
    const int g = blockIdx.x, tid = threadIdx.x, b = g >> 6;
    __shared__ float coordL[NT][NH];
    __shared__ float sceneL[NT][NSC];
    __shared__ float agentL[NT][NAG];
    __shared__ float tyL[NTY];
    const float relv = p.rel[g];
    for (int idx = tid; idx < NT * NH; idx += 512) {
        int r = idx >> 7, k = idx & 127;
        float acc = p.b_in[k];
        const float* nt = p.ntraj + (g * NT + r) * 3;
        const float* tr = p.traj  + (g * NT + r) * 3;
        for (int j = 0; j < 3; ++j) acc += nt[j] * p.W_in[j * NH + k] + tr[j] * p.W_in[(3 + j) * NH + k];
        coordL[r][k] = fmaxf(acc, 0.f);
    }
    for (int i = tid; i < NT * NSC; i += 512) { int r = i >> 5, k = i & 31; sceneL[r][k] = p.sd[(b * NT + r) * NSC + k]; }
    for (int i = tid; i < NT * NAG; i += 512) { int r = i >> 4, k = i & 15; agentL[r][k] = p.adata[(g * NT + r) * NAG + k] * relv; }
    if (tid < NTY) tyL[tid] = p.ty[g * NTY + tid];
    __syncthreads();
    const int c = tid;
    float base = p.vbase[c] + relv * p.vag[c];
    for (int i = 0; i < NTY; ++i) base += tyL[i] * p.Wty[i * 512 + c];
    const float vbeL = p.vbe[c];
    float acc[NT];
#pragma unroll
    for (int r = 0; r < NT; ++r) acc[r] = base + (r > 0 ? vbeL : 0.f);
    for (int k = 0; k < NH; ++k) { float w = p.W_ih[k * 512 + c];
#pragma unroll
        for (int r = 0; r < NT; ++r) acc[r] += coordL[r][k] * w; }
    for (int k = 0; k < NSC; ++k) { float w = p.Wsc[k * 512 + c];
#pragma unroll
        for (int r = 0; r < NT; ++r) acc[r] += sceneL[r][k] * w; }
    for (int k = 0; k < NAG; ++k) { float w = p.Wag[k * 512 + c];
#pragma unroll
        for (int r = 0; r < NT; ++r) acc[r] += agentL[r][k] * w; }
#pragma unroll
    for (int r = 0; r < NT; ++r) p.Xs[((size_t)(g * NT + r)) * 512 + c] = acc[r];
}

// ---- One recurrence step: 2 rows/block, 256 blocks x 1024 threads, fp32 ----
// Round-9 layout, 4 barriers: out-projection deferred one step (out[t-1] from
// hcur, computed as a third work stream in phase 1, written in phase 2).
// t == NT: tail launch, emits out[NT-1] only.
__global__ __launch_bounds__(1024) void k_step(Params p, int t) {
    const int tid = threadIdx.x;
    const int r0 = blockIdx.x * 2;
    const int b = r0 >> 6;
    const int n = tid & 127;
    const int g8 = tid >> 7;                 // 0..7
    const float* __restrict__ hcur = (t & 1) ? p.h1 : p.h0;
    float* hnxt = (t & 1) ? p.h0 : p.h1;

    __shared__ float lh[2][NH], lR[2][NH], lse[2][NH];
    __shared__ float psum[8][NH];            // batch h-sum partials
    __shared__ float ps2[8][NH];             // shw2 partials
    __shared__ float ps[16][NH];             // stage A partials
    __shared__ float psO[8][NH];             // out-proj partials [kq*2+r]
    __shared__ float lagg[2][NH];
    __shared__ float lgp[2][2][512];

    // ---- Tail: out[NT-1] from hcur ----
    if (t == NT) {
        if (tid < 256) lh[tid >> 7][tid & 127] = hcur[(r0 + (tid >> 7)) * NH + (tid & 127)];
        __syncthreads();
        {
            const int r = g8 & 1, kq = g8 >> 1;
            float s = 0.f;
            const float* wp = p.W_pred + n;
#pragma unroll
            for (int k = 32 * kq; k < 32 * kq + 32; ++k) s += lh[r][k] * wp[k * NH];
            psO[g8][n] = s;
        }
        __syncthreads();
        if (tid < 256) {
            const int rr = tid >> 7, k = tid & 127;
            float v = psO[rr][k] + psO[2 + rr][k] + psO[4 + rr][k] + psO[6 + rr][k] + p.b_pred[k];
            p.out[((size_t)(r0 + rr) * NT + (NT - 1)) * NH + k] = fmaxf(v, 0.f);
        }
        return;
    }

    // Phase 0: own-row state loads + batch h-sum partials.
    if (tid < 256) {
        int rr = tid >> 7, k = tid & 127;
        lh[rr][k]  = hcur[(r0 + rr) * NH + k];
        lR[rr][k]  = p.R [(r0 + rr) * NH + k];
        lse[rr][k] = p.se[(r0 + rr) * NH + k];
    }
    if (t > 0) {
        float s = 0.f;
        const float* hb = hcur + (b * NA + g8 * 8) * NH + n;
#pragma unroll
        for (int j = 0; j < 8; ++j) s += hb[j * NH];
        psum[g8][n] = s;
    }
    __syncthreads();                          // B1

    // Phase 1: stage A partials + shw2 partials + out[t-1] partials (from hcur rows).
    if (t > 0) {
        float s = 0.f;
        const float* w2 = p.W_edge + NH * NH + n;
#pragma unroll
        for (int k = 16 * g8; k < 16 * g8 + 16; ++k) {
            float hv = psum[0][k] + psum[1][k] + psum[2][k] + psum[3][k]
                     + psum[4][k] + psum[5][k] + psum[6][k] + psum[7][k];
            s += hv * w2[k * NH];
        }
        ps2[g8][n] = s;
    }
    {
        const int path = g8 >> 1, kh = g8 & 1;
        const float* wb; const float* d0; const float* d1;
        if (path == 0)      { wb = p.W_edge + n;               d0 = lh[0];  d1 = lh[1];  }
        else if (path == 1) { wb = p.W_edge + 2 * NH * NH + n; d0 = lR[0];  d1 = lR[1];  }
        else if (path == 2) { wb = p.W_self + n;               d0 = lh[0];  d1 = lh[1];  }
        else                { wb = p.W_self + NH * NH + n;     d0 = lse[0]; d1 = lse[1]; }
        float a0 = 0.f, a1 = 0.f;
#pragma unroll 8
        for (int k = 64 * kh; k < 64 * kh + 64; ++k) {
            float w = wb[k * NH];
            a0 += d0[k] * w; a1 += d1[k] * w;
        }
        ps[g8 * 2 + 0][n] = a0;
        ps[g8 * 2 + 1][n] = a1;
    }
    if (t > 0) {
        const int r = g8 & 1, kq = g8 >> 1;
        float s = 0.f;
        const float* wp = p.W_pred + n;
#pragma unroll
        for (int k = 32 * kq; k < 32 * kq + 32; ++k) s += lh[r][k] * wp[k * NH];
        psO[g8][n] = s;
    }
    __syncthreads();                          // B2

    // Phase 2: combine shw2 + R_new/se_new/agg; write out[t-1] (threads 512-767).
    if (tid < 256) {
        int rr = tid >> 7, k = tid & 127;
        float shw2v = 0.f;
        if (t > 0) {
#pragma unroll
            for (int q = 0; q < 8; ++q) shw2v += ps2[q][k];
        }
        float a1v = ps[0 + rr][k] + ps[2 + rr][k];
        float a3v = ps[4 + rr][k] + ps[6 + rr][k];
        float aSv = ps[8 + rr][k] + ps[10 + rr][k]
                  + ps[12 + rr][k] + ps[14 + rr][k];
        float Rn = 64.f * a1v + shw2v + a3v + 64.f * p.b_edge[k];
        float Sn = aSv + p.sesty[(r0 + rr) * NH + k];
        p.R [(r0 + rr) * NH + k] = Rn;
        p.se[(r0 + rr) * NH + k] = Sn;
        lagg[rr][k] = Rn + Sn;
    } else if (tid >= 512 && tid < 768 && t > 0) {
        const int rc = tid - 512, rr = rc >> 7, k = rc & 127;
        float v = psO[rr][k] + psO[2 + rr][k] + psO[4 + rr][k] + psO[6 + rr][k] + p.b_pred[k];
        p.out[((size_t)(r0 + rr) * NT + (t - 1)) * NH + k] = fmaxf(v, 0.f);
    }
    __syncthreads();                          // B3

    // Phase 3: gates; 512 cols x 2 K-halves, both rows per thread.
    {
        const int c = tid & 511, kh2 = tid >> 9;
        float a0 = 0.f, a1v = 0.f;
        if (kh2 == 0) {
            a0  = p.Xs[((size_t)r0 * NT + t) * 512 + c];
            a1v = p.Xs[((size_t)(r0 + 1) * NT + t) * 512 + c];
        }
        if (t > 0) {
            const float* wc = p.Wcomb + c;
            const float* wh = p.W_hh + c;
#pragma unroll 8
            for (int k = 64 * kh2; k < 64 * kh2 + 64; ++k) {
                float w = wc[k * 512];
                a0 += lagg[0][k] * w; a1v += lagg[1][k] * w;
            }
#pragma unroll 8
            for (int k = 64 * kh2; k < 64 * kh2 + 64; ++k) {
                float w = wh[k * 512];
                a0 += lh[0][k] * w; a1v += lh[1][k] * w;
            }
        }
        lgp[kh2][0][c] = a0;
        lgp[kh2][1][c] = a1v;
    }
    __syncthreads();                          // B4

    // Phase 4: combine K-halves + LSTM elementwise; publish h (kernel ends).
    if (tid < 256) {
        const int rr = tid >> 7, k = tid & 127, g = r0 + rr;
        float gi = lgp[0][rr][k]          + lgp[1][rr][k];
        float gf = lgp[0][rr][NH + k]     + lgp[1][rr][NH + k];
        float gg = lgp[0][rr][2 * NH + k] + lgp[1][rr][2 * NH + k];
        float go = lgp[0][rr][3 * NH + k] + lgp[1][rr][3 * NH + k];
        float si = 1.f / (1.f + expf(-gi));
        float sf = 1.f / (1.f + expf(-gf));
        float so = 1.f / (1.f + expf(-go));
        float cn = sf * p.c[g * NH + k] + si * tanhf(gg);
        float hn = so * tanhf(cn);
        p.c[g * NH + k] = cn;
        hnxt[g * NH + k] = hn;
    }
}

extern "C" void kernel_launch(void* const* d_in, const int* in_sizes, int n_in,
                              void* d_out, int out_size, void* d_ws, size_t ws_size,
                              hipStream_t stream) {
    const float* const* in = (const float* const*)d_in;
    Params p;
    p.traj = in[0]; p.ntraj = in[1]; p.ty = in[2]; p.sd = in[3]; p.adata = in[4]; p.rel = in[5];
    p.W_in = in[6]; p.b_in = in[7]; p.W_nt = in[8]; p.b_nt = in[9];
    p.W_ag = in[10]; p.b_ag = in[11]; p.W_sc = in[12]; p.b_sc = in[13];
    p.W_ein = in[14]; p.b_ein = in[15]; p.W_ety = in[16]; p.b_ety = in[17];
    p.W_edge = in[18]; p.b_edge = in[19]; p.W_self = in[20]; p.b_self = in[21];
    p.W_e2n = in[22]; p.b_e2n = in[23];
    p.W_ih = in[24]; p.W_hh = in[25]; p.b_ih = in[26]; p.b_hh = in[27];
    p.W_pred = in[28]; p.b_pred = in[29];

    float* ws = (float*)d_ws;
    const size_t S = (size_t)NB * NA * NH;   // 65536
    p.h0 = ws;                // zeroed by k_prelude
    p.h1 = ws + S;            // written at t=0 before any read
    p.c  = ws + 2 * S;        // zeroed by k_prelude
    p.se = ws + 3 * S;        // zeroed by k_prelude
    p.R  = ws + 4 * S;        // k_prelude
    float* w = ws + 5 * S;
    p.Wty   = w;              w += 8 * 512;
    p.Wsc   = w;              w += 32 * 512;
    p.Wag   = w;              w += 16 * 512;
    p.Wcomb = w;              w += 128 * 512;
    p.vbase = w;              w += 512;
    p.vag   = w;              w += 512;
    p.vbe   = w;              w += 512;
    p.sesty = w;              w += (size_t)NB * NA * NH;
    p.Xs    = w;              w += (size_t)NB * NA * NT * 512;
    p.out = (float*)d_out;

    k_prelude<<<313, 512, 0, stream>>>(p);                     // fold | r0 | zeros
    k_xstatic<<<NB * NA, 512, 0, stream>>>(p);
    for (int t = 0; t < NT; ++t)
        k_step<<<NB * NA / 2, 1024, 0, stream>>>(p, t);
    k_step<<<NB * NA / 2, 1024, 0, stream>>>(p, NT);           // tail: out[11]
}

// Round 13
// 189.669 us; speedup vs baseline: 1.2392x; 1.0135x over previous
//
#include <hip/hip_runtime.h>

constexpr int NB = 8, NA = 64, NT = 12, NH = 128, NTY = 8, NSC = 32, NAG = 16;

struct Params {
    const float *traj, *ntraj, *ty, *sd, *adata, *rel;
    const float *W_in, *b_in, *W_nt, *b_nt, *W_ag, *b_ag, *W_sc, *b_sc;
    const float *W_ein, *b_ein, *W_ety, *b_ety;
    const float *W_edge, *b_edge, *W_self, *b_self, *W_e2n, *b_e2n;
    const float *W_ih, *W_hh, *b_ih, *b_hh, *W_pred, *b_pred;
    float *h0, *h1, *c, *se, *R;
    float *Wty, *Wsc, *Wag, *Wcomb, *vbase, *vag, *vbe, *sesty, *Xs, *out;
};

// ---- Prelude: fold (blk 0-184) | r0+sesty+state-zero (blk 185-312, 4 rows/block) ----
__global__ __launch_bounds__(512) void k_prelude(Params p) {
    const int blk = blockIdx.x, tid = threadIdx.x;
    if (blk < 185) {
        const int c = tid;
        __shared__ float lrow[NH];
        __shared__ float b1[NH], b2[NH], b3[NH], b4[NH];
        if (blk < 184) {
            const float* src; int ihoff, row; float* dst;
            if (blk < 8)       { row = blk;      src = p.W_nt  + row * NH; ihoff = 128; dst = p.Wty; }
            else if (blk < 40) { row = blk - 8;  src = p.W_sc  + row * NH; ihoff = 384; dst = p.Wsc; }
            else if (blk < 56) { row = blk - 40; src = p.W_ag  + row * NH; ihoff = 512; dst = p.Wag; }
            else               { row = blk - 56; src = p.W_e2n + row * NH; ihoff = 256; dst = p.Wcomb; }
            if (c < NH) lrow[c] = src[c];
            __syncthreads();
            float acc = 0.f;
            for (int k = 0; k < NH; ++k) acc += lrow[k] * p.W_ih[(ihoff + k) * 512 + c];
            dst[row * 512 + c] = acc;
        } else {
            if (c < NH) { b1[c] = p.b_nt[c]; b2[c] = p.b_sc[c]; b3[c] = p.b_ag[c]; b4[c] = p.b_e2n[c]; }
            __syncthreads();
            float vb = p.b_ih[c] + p.b_hh[c], va = 0.f, ve = 0.f;
            for (int k = 0; k < NH; ++k) {
                vb += b1[k] * p.W_ih[(128 + k) * 512 + c] + b2[k] * p.W_ih[(384 + k) * 512 + c];
                va += b3[k] * p.W_ih[(512 + k) * 512 + c];
                ve += b4[k] * p.W_ih[(256 + k) * 512 + c];
            }
            p.vbase[c] = vb; p.vag[c] = va; p.vbe[c] = ve;
        }
    } else {
        const int r0g = (blk - 185) * 4;
        const int b = r0g >> 6;
        const int q = tid >> 7, n = tid & 127;
        const int row = r0g + q, i = row & 63;
        __shared__ float lf[NA][6];
        __shared__ float lt[NA][NTY];
        __shared__ float sumf[6], sumt[NTY];
        if (tid < NA) {
            int j = tid, rj = b * NA + j;
            for (int k = 0; k < 3; ++k) {
                lf[j][k]     = p.ntraj[(rj * NT + 0) * 3 + k];
                lf[j][3 + k] = p.traj [(rj * NT + 0) * 3 + k];
            }
            for (int k = 0; k < NTY; ++k) lt[j][k] = p.ty[rj * NTY + k];
        }
        p.h0[row * NH + n] = 0.f;
        p.c [row * NH + n] = 0.f;
        p.se[row * NH + n] = 0.f;
        __syncthreads();
        if (tid < 6) {
            float s = 0.f; for (int j = 0; j < NA; ++j) s += lf[j][tid];
            sumf[tid] = s;
        } else if (tid < 6 + NTY) {
            int k = tid - 6; float s = 0.f;
            for (int j = 0; j < NA; ++j) s += lt[j][k];
            sumt[k] = s;
        }
        __syncthreads();
        float acc_i = p.b_ein[n] + p.b_ety[n];
        for (int k = 0; k < 6; ++k)   acc_i += lf[i][k] * p.W_ein[k * NH + n];
        for (int k = 0; k < NTY; ++k) acc_i += lt[i][k] * (p.W_ein[(12 + k) * NH + n] + p.W_ety[k * NH + n]);
        float acc_j = 0.f;
        for (int k = 0; k < 6; ++k)   acc_j += sumf[k] * p.W_ein[(6 + k) * NH + n];
        for (int k = 0; k < NTY; ++k) acc_j += sumt[k] * (p.W_ein[(20 + k) * NH + n] + p.W_ety[(NTY + k) * NH + n]);
        p.R[row * NH + n] = 64.f * acc_i + acc_j;
        float sv = p.b_self[n];
        for (int k = 0; k < NTY; ++k) sv += lt[i][k] * p.W_self[(2 * NH + k) * NH + n];
        p.sesty[row * NH + n] = sv;
    }
}

// ---- X_static[(g,t), 512]; vbe folded in for t>0 ----
__global__ __launch_bounds__(512) void k_xstatic(Params p) {
    const int g = blockIdx.x, tid = threadIdx.x, b = g >> 6;
    __shared__ float coordL[NT][NH];
    __shared__ float sceneL[NT][NSC];
    __shared__ float agentL[NT][NAG];
    __shared__ float tyL[NTY];
    const float relv = p.rel[g];
    for (int idx = tid; idx < NT * NH; idx += 512) {
        int r = idx >> 7, k = idx & 127;
        float acc = p.b_in[k];
        const float* nt = p.ntraj + (g * NT + r) * 3;
        const float* tr = p.traj  + (g * NT + r) * 3;
        for (int j = 0; j < 3; ++j) acc += nt[j] * p.W_in[j * NH + k] + tr[j] * p.W_in[(3 + j) * NH + k];
        coordL[r][k] = fmaxf(acc, 0.f);
    }
    for (int i = tid; i < NT * NSC; i += 512) { int r = i >> 5, k = i & 31; sceneL[r][k] = p.sd[(b * NT + r) * NSC + k]; }
    for (int i = tid; i < NT * NAG; i += 512) { int r = i >> 4, k = i & 15; agentL[r][k] = p.adata[(g * NT + r) * NAG + k] * relv; }
    if (tid < NTY) tyL[tid] = p.ty[g * NTY + tid];
    __syncthreads();
    const int c = tid;
    float base = p.vbase[c] + relv * p.vag[c];
    for (int i = 0; i < NTY; ++i) base += tyL[i] * p.Wty[i * 512 + c];
    const float vbeL = p.vbe[c];
    float acc[NT];
#pragma unroll
    for (int r = 0; r < NT; ++r) acc[r] = base + (r > 0 ? vbeL : 0.f);
    for (int k = 0; k < NH; ++k) { float w = p.W_ih[k * 512 + c];
#pragma unroll
        for (int r = 0; r < NT; ++r) acc[r] += coordL[r][k] * w; }
    for (int k = 0; k < NSC; ++k) { float w = p.Wsc[k * 512 + c];
#pragma unroll
        for (int r = 0; r < NT; ++r) acc[r] += sceneL[r][k] * w; }
    for (int k = 0; k < NAG; ++k) { float w = p.Wag[k * 512 + c];
#pragma unroll
        for (int r = 0; r < NT; ++r) acc[r] += agentL[r][k] * w; }
#pragma unroll
    for (int r = 0; r < NT; ++r) p.Xs[((size_t)(g * NT + r)) * 512 + c] = acc[r];
}

// ---- One recurrence step: 2 rows/block, 256 blocks x 1024 threads, fp32 ----
// Round-12 structure; stage A and gates use float4 weight loads (4x fewer
// load instructions, 4x deeper MLP). t == NT: tail emits out[NT-1].
__global__ __launch_bounds__(1024) void k_step(Params p, int t) {
    const int tid = threadIdx.x;
    const int r0 = blockIdx.x * 2;
    const int b = r0 >> 6;
    const int n = tid & 127;
    const int g8 = tid >> 7;                 // 0..7
    const float* __restrict__ hcur = (t & 1) ? p.h1 : p.h0;
    float* hnxt = (t & 1) ? p.h0 : p.h1;

    __shared__ float lh[2][NH], lR[2][NH], lse[2][NH];
    __shared__ float psum[8][NH];                          // batch h-sum partials
    __shared__ float ps2[8][NH];                           // shw2 partials
    __shared__ __align__(16) float psA[4][8][2][NH];       // stage A partials [path][kq][row]
    __shared__ float psO[8][NH];                           // out-proj partials [kq*2+r]
    __shared__ float lagg[2][NH];
    __shared__ __align__(16) float lgp[8][2][512];         // gate partials [kq][row][col]

    // ---- Tail: out[NT-1] from hcur ----
    if (t == NT) {
        if (tid < 256) lh[tid >> 7][tid & 127] = hcur[(r0 + (tid >> 7)) * NH + (tid & 127)];
        __syncthreads();
        {
            const int r = g8 & 1, kq = g8 >> 1;
            float s = 0.f;
            const float* wp = p.W_pred + n;
#pragma unroll
            for (int k = 32 * kq; k < 32 * kq + 32; ++k) s += lh[r][k] * wp[k * NH];
            psO[g8][n] = s;
        }
        __syncthreads();
        if (tid < 256) {
            const int rr = tid >> 7, k = tid & 127;
            float v = psO[rr][k] + psO[2 + rr][k] + psO[4 + rr][k] + psO[6 + rr][k] + p.b_pred[k];
            p.out[((size_t)(r0 + rr) * NT + (NT - 1)) * NH + k] = fmaxf(v, 0.f);
        }
        return;
    }

    // Phase 0: own-row state loads + batch h-sum partials.
    if (tid < 256) {
        int rr = tid >> 7, k = tid & 127;
        lh[rr][k]  = hcur[(r0 + rr) * NH + k];
        lR[rr][k]  = p.R [(r0 + rr) * NH + k];
        lse[rr][k] = p.se[(r0 + rr) * NH + k];
    }
    if (t > 0) {
        float s = 0.f;
        const float* hb = hcur + (b * NA + g8 * 8) * NH + n;
#pragma unroll
        for (int j = 0; j < 8; ++j) s += hb[j * NH];
        psum[g8][n] = s;
    }
    __syncthreads();                          // B1

    // Phase 1: stage A (float4) + shw2 + out[t-1] partials.
    {
        const int pa  = tid >> 8;             // 0..3 path
        const int kq  = (tid >> 5) & 7;       // K-eighth
        const int t32 = tid & 31;             // col-quad
        const float* wb = (pa == 0) ? p.W_edge
                        : (pa == 1) ? p.W_edge + 2 * NH * NH
                        : (pa == 2) ? p.W_self
                                    : p.W_self + NH * NH;
        const float* d0 = (pa == 1) ? lR[0] : (pa == 3) ? lse[0] : lh[0];
        const float* d1 = (pa == 1) ? lR[1] : (pa == 3) ? lse[1] : lh[1];
        const float4* wv = (const float4*)wb;
        float4 a0 = {0.f, 0.f, 0.f, 0.f}, a1 = {0.f, 0.f, 0.f, 0.f};
#pragma unroll
        for (int k = 16 * kq; k < 16 * kq + 16; ++k) {
            float4 w4 = wv[k * 32 + t32];
            float x0 = d0[k], x1 = d1[k];
            a0.x += x0 * w4.x; a0.y += x0 * w4.y; a0.z += x0 * w4.z; a0.w += x0 * w4.w;
            a1.x += x1 * w4.x; a1.y += x1 * w4.y; a1.z += x1 * w4.z; a1.w += x1 * w4.w;
        }
        *(float4*)&psA[pa][kq][0][4 * t32] = a0;
        *(float4*)&psA[pa][kq][1][4 * t32] = a1;
    }
    if (t > 0) {
        float s = 0.f;
        const float* w2 = p.W_edge + NH * NH + n;
#pragma unroll
        for (int k = 16 * g8; k < 16 * g8 + 16; ++k) {
            float hv = psum[0][k] + psum[1][k] + psum[2][k] + psum[3][k]
                     + psum[4][k] + psum[5][k] + psum[6][k] + psum[7][k];
            s += hv * w2[k * NH];
        }
        ps2[g8][n] = s;
    }
    if (t > 0) {
        const int r = g8 & 1, kq = g8 >> 1;
        float s = 0.f;
        const float* wp = p.W_pred + n;
#pragma unroll
        for (int k = 32 * kq; k < 32 * kq + 32; ++k) s += lh[r][k] * wp[k * NH];
        psO[g8][n] = s;
    }
    __syncthreads();                          // B2

    // Phase 2: combine shw2 + R_new/se_new/agg; write out[t-1] (threads 512-767).
    if (tid < 256) {
        int rr = tid >> 7, k = tid & 127;
        float shw2v = 0.f;
        if (t > 0) {
#pragma unroll
            for (int q = 0; q < 8; ++q) shw2v += ps2[q][k];
        }
        float a1v = 0.f, a3v = 0.f, aSv = 0.f;
#pragma unroll
        for (int kq = 0; kq < 8; ++kq) {
            a1v += psA[0][kq][rr][k];
            a3v += psA[1][kq][rr][k];
            aSv += psA[2][kq][rr][k] + psA[3][kq][rr][k];
        }
        float Rn = 64.f * a1v + shw2v + a3v + 64.f * p.b_edge[k];
        float Sn = aSv + p.sesty[(r0 + rr) * NH + k];
        p.R [(r0 + rr) * NH + k] = Rn;
        p.se[(r0 + rr) * NH + k] = Sn;
        lagg[rr][k] = Rn + Sn;
    } else if (tid >= 512 && tid < 768 && t > 0) {
        const int rc = tid - 512, rr = rc >> 7, k = rc & 127;
        float v = psO[rr][k] + psO[2 + rr][k] + psO[4 + rr][k] + psO[6 + rr][k] + p.b_pred[k];
        p.out[((size_t)(r0 + rr) * NT + (t - 1)) * NH + k] = fmaxf(v, 0.f);
    }
    __syncthreads();                          // B3

    // Phase 3: gates (float4); 8 K-eighths x 128 col-quads, both rows per thread.
    {
        const int kq = tid >> 7;              // K-eighth
        const int cq = tid & 127;             // col-quad (cols 4cq..4cq+3)
        float4 a0 = {0.f, 0.f, 0.f, 0.f}, a1 = {0.f, 0.f, 0.f, 0.f};
        if (kq == 0) {
            a0 = *(const float4*)&p.Xs[((size_t)r0 * NT + t) * 512 + 4 * cq];
            a1 = *(const float4*)&p.Xs[((size_t)(r0 + 1) * NT + t) * 512 + 4 * cq];
        }
        if (t > 0) {
            const float4* wc = (const float4*)p.Wcomb;
            const float4* wh = (const float4*)p.W_hh;
#pragma unroll
            for (int k = 16 * kq; k < 16 * kq + 16; ++k) {
                float4 w4 = wc[k * 128 + cq];
                float g0 = lagg[0][k], g1 = lagg[1][k];
                a0.x += g0 * w4.x; a0.y += g0 * w4.y; a0.z += g0 * w4.z; a0.w += g0 * w4.w;
                a1.x += g1 * w4.x; a1.y += g1 * w4.y; a1.z += g1 * w4.z; a1.w += g1 * w4.w;
            }
#pragma unroll
            for (int k = 16 * kq; k < 16 * kq + 16; ++k) {
                float4 w4 = wh[k * 128 + cq];
                float h0v = lh[0][k], h1v = lh[1][k];
                a0.x += h0v * w4.x; a0.y += h0v * w4.y; a0.z += h0v * w4.z; a0.w += h0v * w4.w;
                a1.x += h1v * w4.x; a1.y += h1v * w4.y; a1.z += h1v * w4.z; a1.w += h1v * w4.w;
            }
        }
        *(float4*)&lgp[kq][0][4 * cq] = a0;
        *(float4*)&lgp[kq][1][4 * cq] = a1;
    }
    __syncthreads();                          // B4

    // Phase 4: combine 8 K-eighths + LSTM elementwise; publish h.
    if (tid < 256) {
        const int rr = tid >> 7, k = tid & 127, g = r0 + rr;
        float gi = 0.f, gf = 0.f, gg = 0.f, go = 0.f;
#pragma unroll
        for (int kq = 0; kq < 8; ++kq) {
            gi += lgp[kq][rr][k];
            gf += lgp[kq][rr][NH + k];
            gg += lgp[kq][rr][2 * NH + k];
            go += lgp[kq][rr][3 * NH + k];
        }
        float si = 1.f / (1.f + expf(-gi));
        float sf = 1.f / (1.f + expf(-gf));
        float so = 1.f / (1.f + expf(-go));
        float cn = sf * p.c[g * NH + k] + si * tanhf(gg);
        float hn = so * tanhf(cn);
        p.c[g * NH + k] = cn;
        hnxt[g * NH + k] = hn;
    }
}

extern "C" void kernel_launch(void* const* d_in, const int* in_sizes, int n_in,
                              void* d_out, int out_size, void* d_ws, size_t ws_size,
                              hipStream_t stream) {
    const float* const* in = (const float* const*)d_in;
    Params p;
    p.traj = in[0]; p.ntraj = in[1]; p.ty = in[2]; p.sd = in[3]; p.adata = in[4]; p.rel = in[5];
    p.W_in = in[6]; p.b_in = in[7]; p.W_nt = in[8]; p.b_nt = in[9];
    p.W_ag = in[10]; p.b_ag = in[11]; p.W_sc = in[12]; p.b_sc = in[13];
    p.W_ein = in[14]; p.b_ein = in[15]; p.W_ety = in[16]; p.b_ety = in[17];
    p.W_edge = in[18]; p.b_edge = in[19]; p.W_self = in[20]; p.b_self = in[21];
    p.W_e2n = in[22]; p.b_e2n = in[23];
    p.W_ih = in[24]; p.W_hh = in[25]; p.b_ih = in[26]; p.b_hh = in[27];
    p.W_pred = in[28]; p.b_pred = in[29];

    float* ws = (float*)d_ws;
    const size_t S = (size_t)NB * NA * NH;   // 65536
    p.h0 = ws;                // zeroed by k_prelude
    p.h1 = ws + S;            // written at t=0 before any read
    p.c  = ws + 2 * S;        // zeroed by k_prelude
    p.se = ws + 3 * S;        // zeroed by k_prelude
    p.R  = ws + 4 * S;        // k_prelude
    float* w = ws + 5 * S;
    p.Wty   = w;              w += 8 * 512;
    p.Wsc   = w;              w += 32 * 512;
    p.Wag   = w;              w += 16 * 512;
    p.Wcomb = w;              w += 128 * 512;
    p.vbase = w;              w += 512;
    p.vag   = w;              w += 512;
    p.vbe   = w;              w += 512;
    p.sesty = w;              w += (size_t)NB * NA * NH;
    p.Xs    = w;              w += (size_t)NB * NA * NT * 512;
    p.out = (float*)d_out;

    k_prelude<<<313, 512, 0, stream>>>(p);                     // fold | r0 | zeros
    k_xstatic<<<NB * NA, 512, 0, stream>>>(p);
    for (int t = 0; t < NT; ++t)
        k_step<<<NB * NA / 2, 1024, 0, stream>>>(p, t);
    k_step<<<NB * NA / 2, 1024, 0, stream>>>(p, NT);           // tail: out[11]
}